// Round 13
// baseline (1976.699 us; speedup 1.0000x reference)
//
#include <hip/hip_runtime.h>
#include <math.h>

// Shapes:
// x:  [8, 2, 2048, 256]
// L1: conv k(8,1) s(4,1) p(2,0): -> [8,48,512,256]; gelu; 1x1 ->96; GLU -> [8,48,512,256]  (y1, ws)
// L2: conv -> [8,96,128,256]; gelu (g2, staged in d_out latent region); 1x1 ->192; GLU -> beforvq (d_out)
// VQ: argmin over 1024 codes of ||f - c||^2, latent = codebook[idx]
//
// d_out layout (fp32): latent [25165824] | indices-as-float [262144] | beforvq [25165824]

#define H1IN 2048
#define H1OUT 512
#define H2IN 512
#define H2OUT 128
#define TT 256
#define NPTS 32768           // 128*256 per batch
#define LAT_ELEMS 25165824   // 8*96*128*256
#define IDX_ELEMS 262144

typedef unsigned int uint;
typedef unsigned short ushort_t;
typedef __attribute__((ext_vector_type(8))) short bf16x8;
typedef __attribute__((ext_vector_type(4))) float f32x4;

// fp32 -> bf16 round-to-nearest-even (finite inputs)
__device__ __forceinline__ ushort_t f2bf(float x) {
    uint u = __float_as_uint(x);
    return (ushort_t)((u + 0x7fffu + ((u >> 16) & 1u)) >> 16);
}
__device__ __forceinline__ float bf2f(ushort_t h) {
    return __uint_as_float((uint)h << 16);
}

// ---------------- prep: transpose weights, codebook norms ----------------
__global__ __launch_bounds__(256) void prep_kernel(
    const float* __restrict__ w1, const float* __restrict__ w2,
    const float* __restrict__ w3, const float* __restrict__ w4,
    const float* __restrict__ cb,
    float* __restrict__ w1t, float* __restrict__ w2t,
    float* __restrict__ w3t, float* __restrict__ w4t,
    float* __restrict__ cnorm)
{
    int i = blockIdx.x * 256 + threadIdx.x;
    if (i < 768) {                       // w1t[(ci*8+kh)*48+oc] = w1[(oc*2+ci)*8+kh]
        int oc = i % 48; int r = i / 48;
        w1t[i] = w1[(oc * 2 + (r >> 3)) * 8 + (r & 7)];
    } else if (i < 5376) {               // w2t[c*96+oc] = w2[oc*48+c]
        int j = i - 768;
        int oc = j % 96, c = j / 96;
        w2t[j] = w2[oc * 48 + c];
    } else if (i < 42240) {              // w3t[(ci*8+kh)*96+oc] = w3[(oc*48+ci)*8+kh]
        int j = i - 5376;
        int oc = j % 96; int r = j / 96;
        w3t[j] = w3[(oc * 48 + (r >> 3)) * 8 + (r & 7)];
    } else if (i < 60672) {              // w4t[c*192+oc] = w4[oc*96+c]
        int j = i - 42240;
        int oc = j % 192, c = j / 192;
        w4t[j] = w4[oc * 96 + c];
    } else if (i < 61696) {              // cnorm[k] = sum_d cb[k][d]^2 (fp64 accumulate)
        int k = i - 60672;
        const float* cp = cb + (size_t)k * 96;
        double s = 0.0;
        for (int d = 0; d < 96; d++) s += (double)cp[d] * (double)cp[d];
        cnorm[k] = (float)s;
    }
}

__device__ __forceinline__ float gelu_tanh(float v) {
    float u = 0.7978845608028654f * (v + 0.044715f * v * v * v);
    return 0.5f * v * (1.f + tanhf(u));
}

// ---------------- layer 1 fused: conv + gelu + 1x1 + GLU ----------------
__global__ __launch_bounds__(256, 2) void henc1_kernel(
    const float* __restrict__ x, const float* __restrict__ w1t,
    const float* __restrict__ b1, const float* __restrict__ w2t,
    const float* __restrict__ b2, float* __restrict__ y1)
{
    __shared__ float gs[48 * 256];
    int bh = blockIdx.x;           // b*512 + ho
    int ho = bh & 511, b = bh >> 9;
    int t = threadIdx.x;

    float g[48];
#pragma unroll
    for (int oc = 0; oc < 48; oc++) g[oc] = b1[oc];

    const float* xb = x + (size_t)b * 2 * H1IN * TT;
    int hbase = ho * 4 - 2;
    for (int ci = 0; ci < 2; ci++) {
        for (int kh = 0; kh < 8; kh++) {
            int hi = hbase + kh;
            float v = (hi >= 0 && hi < H1IN) ? xb[((size_t)ci * H1IN + hi) * TT + t] : 0.f;
            const float* wp = w1t + (ci * 8 + kh) * 48;
#pragma unroll
            for (int oc = 0; oc < 48; oc++) g[oc] = fmaf(v, wp[oc], g[oc]);
        }
    }
#pragma unroll
    for (int oc = 0; oc < 48; oc++) gs[oc * 256 + t] = gelu_tanh(g[oc]);

    float z[96];
#pragma unroll
    for (int oc = 0; oc < 96; oc++) z[oc] = b2[oc];
    for (int c = 0; c < 48; c++) {
        float v = gs[c * 256 + t];
        const float* wp = w2t + c * 96;
#pragma unroll
        for (int oc = 0; oc < 96; oc++) z[oc] = fmaf(v, wp[oc], z[oc]);
    }

    float* yb = y1 + (size_t)b * 48 * H1OUT * TT + (size_t)ho * TT + t;
#pragma unroll
    for (int co = 0; co < 48; co++) {
        float o = z[co] / (1.f + expf(-z[co + 48]));   // a * sigmoid(b)
        yb[(size_t)co * H1OUT * TT] = o;
    }
}

// ---------------- layer 2 conv + gelu ----------------
__global__ __launch_bounds__(256, 2) void conv2a_kernel(
    const float* __restrict__ y1, const float* __restrict__ w3t,
    const float* __restrict__ b3, float* __restrict__ g2)
{
    int bh = blockIdx.x;           // b*128 + ho
    int ho = bh & 127, b = bh >> 7;
    int t = threadIdx.x;

    float g[96];
#pragma unroll
    for (int oc = 0; oc < 96; oc++) g[oc] = b3[oc];

    const float* xb = y1 + (size_t)b * 48 * H2IN * TT;
    int hbase = ho * 4 - 2;
    for (int kh = 0; kh < 8; kh++) {
        int hi = hbase + kh;
        if (hi < 0 || hi >= H2IN) continue;       // wave-uniform branch
        const float* xr = xb + (size_t)hi * TT + t;
        for (int ci = 0; ci < 48; ci++) {
            float v = xr[(size_t)ci * H2IN * TT];
            const float* wp = w3t + (ci * 8 + kh) * 96;
#pragma unroll
            for (int oc = 0; oc < 96; oc++) g[oc] = fmaf(v, wp[oc], g[oc]);
        }
    }

    float* gp = g2 + (size_t)b * 96 * NPTS + (size_t)ho * TT + t;
#pragma unroll
    for (int oc = 0; oc < 96; oc++) gp[(size_t)oc * NPTS] = gelu_tanh(g[oc]);
}

// ---------------- layer 2 rewrite (1x1 -> 192) + GLU + bf16 hi/lo emit ----
__global__ __launch_bounds__(256, 2) void rw2b_kernel(
    const float* __restrict__ g2, const float* __restrict__ w4t,
    const float* __restrict__ b4, float* __restrict__ outv,
    const float* __restrict__ cb,
    ushort_t* __restrict__ fh, ushort_t* __restrict__ fl,
    ushort_t* __restrict__ cbh, ushort_t* __restrict__ cbl)
{
    int i = blockIdx.x * 256 + threadIdx.x;   // 0 .. 262143
    if (i < 98304) {                          // codebook bf16 hi/lo split
        float xv = cb[i];
        ushort_t h = f2bf(xv);
        cbh[i] = h;
        cbl[i] = f2bf(xv - bf2f(h));
    }

    int b = i >> 15, p = i & 32767;
    const float* gp = g2 + (size_t)b * 96 * NPTS + p;
    float* op = outv + (size_t)b * 96 * NPTS + p;

    for (int half = 0; half < 2; half++) {
        float za[48], zb[48];
#pragma unroll
        for (int j = 0; j < 48; j++) {
            za[j] = b4[half * 48 + j];
            zb[j] = b4[96 + half * 48 + j];
        }
        for (int c = 0; c < 96; c++) {
            float v = gp[(size_t)c * NPTS];
            const float* wp = w4t + c * 192;
#pragma unroll
            for (int j = 0; j < 48; j++) {
                za[j] = fmaf(v, wp[half * 48 + j], za[j]);
                zb[j] = fmaf(v, wp[96 + half * 48 + j], zb[j]);
            }
        }
        uint* fhp = (uint*)(fh + (size_t)i * 96 + half * 48);
        uint* flp = (uint*)(fl + (size_t)i * 96 + half * 48);
#pragma unroll
        for (int q = 0; q < 24; q++) {
            float o0 = za[2 * q]     / (1.f + expf(-zb[2 * q]));
            float o1 = za[2 * q + 1] / (1.f + expf(-zb[2 * q + 1]));
            op[(size_t)(half * 48 + 2 * q)     * NPTS] = o0;
            op[(size_t)(half * 48 + 2 * q + 1) * NPTS] = o1;
            ushort_t h0 = f2bf(o0); ushort_t l0 = f2bf(o0 - bf2f(h0));
            ushort_t h1 = f2bf(o1); ushort_t l1 = f2bf(o1 - bf2f(h1));
            fhp[q] = (uint)h0 | ((uint)h1 << 16);
            flp[q] = (uint)l0 | ((uint)l1 << 16);
        }
    }
}

// ---------------- VQ via MFMA: bf16 hi/lo screen + fp64 top-4 rescore ----
// R13 = R12 (PASSED, 477us) + GEMM M-blocking: 32 points/wave (2 A-sets).
// R12 arithmetic: every wave re-read the WHOLE hi/lo codebook (384KB of
// fragment loads) -> 16384 waves x 384KB = 6.3GB of L1/L2 traffic (~180us
// at L2 BW) vs 65us of MFMA-busy; B:MFMA ratio 6:9 with A-reuse of only
// 16 points. Fix: two A-fragment sets per wave -> same 6 B loads feed 18
// MFMAs (two independent chains, better MFMA pipe overlap), codebook
// traffic per point halves. Register audit: A 48 + B dbuf 48 + acc 8 +
// screen 64 + addr ~20 = ~190 -> launch_bounds(256,2) (cap 256, no
// pressure -> no remat/spill; R0/R7 lessons). Occupancy 2 blocks/CU = 25%
// (m97-style tradeoff: reuse over residency).
// Screen/merge/rescue/gather: same verified structure, generalized to 32
// points (mbuf pt = set*16 + lgrp*4 + r; rescue runs 2 rounds).
// Guards: WRITE_SIZE ~99MB (spill watch); vqm gain <40us -> revert to R12
// vqm, pivot to conv pipeline.
__global__ __launch_bounds__(256, 2) void vqm_kernel(
    const float* __restrict__ bq,
    const ushort_t* __restrict__ fh, const ushort_t* __restrict__ fl,
    const ushort_t* __restrict__ cbh, const ushort_t* __restrict__ cbl,
    const float* __restrict__ cb, const float* __restrict__ cnorm,
    float* __restrict__ latent, float* __restrict__ idxf)
{
    __shared__ float mbuf[4][32][8];     // [wave][point][4 s | 4 k]
    int tid = threadIdx.x;
    int lane = tid & 63;
    int wid = __builtin_amdgcn_readfirstlane(tid >> 6);   // 0..3 (R9 lesson)
    int lrow = lane & 15, lgrp = lane >> 4;
    int gp0 = blockIdx.x * 128;          // 2048 blocks; 256/batch -> no straddle
    int b = gp0 >> 15, p0 = gp0 & 32767;
    int pbase = gp0 + wid * 32;          // wave's 32 global points

    // ---- A fragments: two 16-point sets, dims kk*32 + 8*lgrp .. +7 ----
    bf16x8 ah0[3], al0[3], ah1[3], al1[3];
    {
        const ushort_t* ph0 = fh + (size_t)(pbase + lrow) * 96 + 8 * lgrp;
        const ushort_t* pl0 = fl + (size_t)(pbase + lrow) * 96 + 8 * lgrp;
        const ushort_t* ph1 = fh + (size_t)(pbase + 16 + lrow) * 96 + 8 * lgrp;
        const ushort_t* pl1 = fl + (size_t)(pbase + 16 + lrow) * 96 + 8 * lgrp;
#pragma unroll
        for (int kk = 0; kk < 3; kk++) {
            ah0[kk] = *(const bf16x8*)(ph0 + kk * 32);
            al0[kk] = *(const bf16x8*)(pl0 + kk * 32);
            ah1[kk] = *(const bf16x8*)(ph1 + kk * 32);
            al1[kk] = *(const bf16x8*)(pl1 + kk * 32);
        }
    }

    float bs[8][4]; int bk[8][4];        // [set*4+r]: sorted ascending top-4
#pragma unroll
    for (int r = 0; r < 8; r++)
#pragma unroll
        for (int j = 0; j < 4; j++) { bs[r][j] = 3.402823466e+38f; bk[r][j] = 0x7fffffff; }

    // ---- pipelined ct loop: prefetch ct+1 while MFMAing ct ----
    const ushort_t* qh = cbh + (size_t)lrow * 96 + 8 * lgrp;
    const ushort_t* ql = cbl + (size_t)lrow * 96 + 8 * lgrp;
    const float* cnp = cnorm + lrow;

    bf16x8 nbh0 = *(const bf16x8*)(qh);
    bf16x8 nbh1 = *(const bf16x8*)(qh + 32);
    bf16x8 nbh2 = *(const bf16x8*)(qh + 64);
    bf16x8 nbl0 = *(const bf16x8*)(ql);
    bf16x8 nbl1 = *(const bf16x8*)(ql + 32);
    bf16x8 nbl2 = *(const bf16x8*)(ql + 64);
    float ncn = *cnp;

#pragma unroll 1
    for (int ct = 0; ct < 64; ct++) {
        bf16x8 bh0 = nbh0, bh1 = nbh1, bh2 = nbh2;
        bf16x8 bl0 = nbl0, bl1 = nbl1, bl2 = nbl2;
        float cn = ncn;
        int code = ct * 16 + lrow;

        if (ct < 63) {                   // issue next tile's loads early
            qh += 16 * 96; ql += 16 * 96; cnp += 16;
            nbh0 = *(const bf16x8*)(qh);
            nbh1 = *(const bf16x8*)(qh + 32);
            nbh2 = *(const bf16x8*)(qh + 64);
            nbl0 = *(const bf16x8*)(ql);
            nbl1 = *(const bf16x8*)(ql + 32);
            nbl2 = *(const bf16x8*)(ql + 64);
            ncn = *cnp;
        }

        // two independent MFMA chains (interleaved for pipe overlap)
        f32x4 acc0 = {0.f, 0.f, 0.f, 0.f};
        f32x4 acc1 = {0.f, 0.f, 0.f, 0.f};
        acc0 = __builtin_amdgcn_mfma_f32_16x16x32_bf16(ah0[0], bh0, acc0, 0, 0, 0);
        acc1 = __builtin_amdgcn_mfma_f32_16x16x32_bf16(ah1[0], bh0, acc1, 0, 0, 0);
        acc0 = __builtin_amdgcn_mfma_f32_16x16x32_bf16(ah0[1], bh1, acc0, 0, 0, 0);
        acc1 = __builtin_amdgcn_mfma_f32_16x16x32_bf16(ah1[1], bh1, acc1, 0, 0, 0);
        acc0 = __builtin_amdgcn_mfma_f32_16x16x32_bf16(ah0[2], bh2, acc0, 0, 0, 0);
        acc1 = __builtin_amdgcn_mfma_f32_16x16x32_bf16(ah1[2], bh2, acc1, 0, 0, 0);
        acc0 = __builtin_amdgcn_mfma_f32_16x16x32_bf16(ah0[0], bl0, acc0, 0, 0, 0);
        acc1 = __builtin_amdgcn_mfma_f32_16x16x32_bf16(ah1[0], bl0, acc1, 0, 0, 0);
        acc0 = __builtin_amdgcn_mfma_f32_16x16x32_bf16(ah0[1], bl1, acc0, 0, 0, 0);
        acc1 = __builtin_amdgcn_mfma_f32_16x16x32_bf16(ah1[1], bl1, acc1, 0, 0, 0);
        acc0 = __builtin_amdgcn_mfma_f32_16x16x32_bf16(ah0[2], bl2, acc0, 0, 0, 0);
        acc1 = __builtin_amdgcn_mfma_f32_16x16x32_bf16(ah1[2], bl2, acc1, 0, 0, 0);
        acc0 = __builtin_amdgcn_mfma_f32_16x16x32_bf16(al0[0], bh0, acc0, 0, 0, 0);
        acc1 = __builtin_amdgcn_mfma_f32_16x16x32_bf16(al1[0], bh0, acc1, 0, 0, 0);
        acc0 = __builtin_amdgcn_mfma_f32_16x16x32_bf16(al0[1], bh1, acc0, 0, 0, 0);
        acc1 = __builtin_amdgcn_mfma_f32_16x16x32_bf16(al1[1], bh1, acc1, 0, 0, 0);
        acc0 = __builtin_amdgcn_mfma_f32_16x16x32_bf16(al0[2], bh2, acc0, 0, 0, 0);
        acc1 = __builtin_amdgcn_mfma_f32_16x16x32_bf16(al1[2], bh2, acc1, 0, 0, 0);

#pragma unroll
        for (int set = 0; set < 2; set++) {
#pragma unroll
            for (int r = 0; r < 4; r++) {
                float av = set ? acc1[r] : acc0[r];
                float s = fmaf(-2.f, av, cn);
                int idx = set * 4 + r;
                if (s < bs[idx][3]) {    // codes arrive in ascending k; strict <
                    bs[idx][3] = s; bk[idx][3] = code;
                    if (bs[idx][3] < bs[idx][2]) {
                        float ts = bs[idx][2]; bs[idx][2] = bs[idx][3]; bs[idx][3] = ts;
                        int   tk = bk[idx][2]; bk[idx][2] = bk[idx][3]; bk[idx][3] = tk;
                        if (bs[idx][2] < bs[idx][1]) {
                            ts = bs[idx][1]; bs[idx][1] = bs[idx][2]; bs[idx][2] = ts;
                            tk = bk[idx][1]; bk[idx][1] = bk[idx][2]; bk[idx][2] = tk;
                            if (bs[idx][1] < bs[idx][0]) {
                                ts = bs[idx][0]; bs[idx][0] = bs[idx][1]; bs[idx][1] = ts;
                                tk = bk[idx][0]; bk[idx][0] = bk[idx][1]; bk[idx][1] = tk;
                            }
                        }
                    }
                }
            }
        }
    }

    // ---- butterfly merge of sorted top-4 across the 16 lanes (per row) ----
    // (s,k) comparator: smaller s wins; tie -> smaller k (global first-min).
#define CSW(si, ki, sj, kj) { bool c_ = (sj < si) || (sj == si && kj < ki); \
        float ls_ = c_ ? sj : si; float hs_ = c_ ? si : sj;                 \
        int   lk_ = c_ ? kj : ki; int   hk_ = c_ ? ki : kj;                 \
        si = ls_; ki = lk_; sj = hs_; kj = hk_; }
#pragma unroll
    for (int m = 1; m <= 8; m <<= 1) {
#pragma unroll
        for (int r = 0; r < 8; r++) {
            float os0 = __shfl_xor(bs[r][0], m), os1 = __shfl_xor(bs[r][1], m);
            float os2 = __shfl_xor(bs[r][2], m), os3 = __shfl_xor(bs[r][3], m);
            int   ok0 = __shfl_xor(bk[r][0], m), ok1 = __shfl_xor(bk[r][1], m);
            int   ok2 = __shfl_xor(bk[r][2], m), ok3 = __shfl_xor(bk[r][3], m);
            // bitonic stage 1: L_i = min(a_i, o_{3-i}) -> lowest 4, bitonic
            bool t0 = (bs[r][0] < os3) || (bs[r][0] == os3 && bk[r][0] < ok3);
            bool t1 = (bs[r][1] < os2) || (bs[r][1] == os2 && bk[r][1] < ok2);
            bool t2 = (bs[r][2] < os1) || (bs[r][2] == os1 && bk[r][2] < ok1);
            bool t3 = (bs[r][3] < os0) || (bs[r][3] == os0 && bk[r][3] < ok0);
            float L0s = t0 ? bs[r][0] : os3;  int L0k = t0 ? bk[r][0] : ok3;
            float L1s = t1 ? bs[r][1] : os2;  int L1k = t1 ? bk[r][1] : ok2;
            float L2s = t2 ? bs[r][2] : os1;  int L2k = t2 ? bk[r][2] : ok1;
            float L3s = t3 ? bs[r][3] : os0;  int L3k = t3 ? bk[r][3] : ok0;
            // bitonic sort-4
            CSW(L0s, L0k, L2s, L2k); CSW(L1s, L1k, L3s, L3k);
            CSW(L0s, L0k, L1s, L1k); CSW(L2s, L2k, L3s, L3k);
            bs[r][0] = L0s; bk[r][0] = L0k; bs[r][1] = L1s; bk[r][1] = L1k;
            bs[r][2] = L2s; bk[r][2] = L2k; bs[r][3] = L3s; bk[r][3] = L3k;
        }
    }
#undef CSW

    if (lrow == 0) {
#pragma unroll
        for (int set = 0; set < 2; set++) {
#pragma unroll
            for (int r = 0; r < 4; r++) {
                int pt = set * 16 + lgrp * 4 + r;
                int idx = set * 4 + r;
#pragma unroll
                for (int j = 0; j < 4; j++) {
                    mbuf[wid][pt][j] = bs[idx][j];
                    mbuf[wid][pt][4 + j] = (float)bk[idx][j];   // k<=1023 exact
                }
            }
        }
    }
    __syncthreads();

    // ---- fp64 rescore of the 4 candidates; 2 rounds of 16 points ----
#pragma unroll 1
    for (int q = 0; q < 2; q++) {
        int p = lrow + 16 * q;
        int kj = (int)mbuf[wid][p][4 + lgrp];
        const float* fpt = bq + (size_t)b * 96 * NPTS + (p0 + wid * 32 + p);
        const float* cj = cb + (size_t)kj * 96;
        double sd = 0.0;
        for (int d = 0; d < 96; d++) {
            double fd = (double)fpt[(size_t)d * NPTS];
            double xv = (double)cj[d];
            sd = fma(xv, xv - 2.0 * fd, sd);
        }
#pragma unroll
        for (int m = 16; m <= 32; m <<= 1) {
            double so = __shfl_xor(sd, m);
            int    ko = __shfl_xor(kj, m);
            if (so < sd || (so == sd && ko < kj)) { sd = so; kj = ko; }
        }
        if (lgrp == 0) idxf[gp0 + wid * 32 + p] = (float)kj;

        // gather: lane writes 24 channels of its point
        const float* cbest = cb + (size_t)kj * 96;
        float* lp = latent + (size_t)b * 96 * NPTS + (p0 + wid * 32 + p);
#pragma unroll
        for (int i = 0; i < 24; i++) {
            int c = lgrp * 24 + i;
            lp[(size_t)c * NPTS] = cbest[c];
        }
    }
}

extern "C" void kernel_launch(void* const* d_in, const int* in_sizes, int n_in,
                              void* d_out, int out_size, void* d_ws, size_t ws_size,
                              hipStream_t stream) {
    const float* x  = (const float*)d_in[0];
    const float* w1 = (const float*)d_in[1];
    const float* b1 = (const float*)d_in[2];
    const float* w2 = (const float*)d_in[3];
    const float* b2 = (const float*)d_in[4];
    const float* w3 = (const float*)d_in[5];
    const float* b3 = (const float*)d_in[6];
    const float* w4 = (const float*)d_in[7];
    const float* b4 = (const float*)d_in[8];
    const float* cb = (const float*)d_in[9];

    float* ws    = (float*)d_ws;
    float* y1    = ws;                       // 50331648 floats (201 MB); dead after conv2a
    float* w1t   = ws + 50331648;            // 768
    float* w2t   = w1t + 768;                // 4608
    float* w3t   = w2t + 4608;               // 36864
    float* w4t   = w3t + 36864;              // 18432
    float* cnorm = w4t + 18432;              // 1024

    // bf16 planes live in the dead y1 region (written by rw2b, after conv2a):
    ushort_t* fh  = (ushort_t*)ws;                    // 25165824 bf16 = 12582912 floats
    ushort_t* fl  = (ushort_t*)(ws + 12582912);       // 25165824 bf16
    ushort_t* cbh = (ushort_t*)(ws + 25165824);       // 98304 bf16 = 49152 floats
    ushort_t* cbl = (ushort_t*)(ws + 25165824 + 49152);

    float* out    = (float*)d_out;
    float* latent = out;
    float* idxf   = out + LAT_ELEMS;
    float* bq     = out + LAT_ELEMS + IDX_ELEMS;
    float* g2     = latent;   // latent region dead until vqm; reuse as conv2 scratch

    prep_kernel<<<241, 256, 0, stream>>>(w1, w2, w3, w4, cb, w1t, w2t, w3t, w4t, cnorm);
    henc1_kernel<<<8 * 512, 256, 0, stream>>>(x, w1t, b1, w2t, b2, y1);
    conv2a_kernel<<<8 * 128, 256, 0, stream>>>(y1, w3t, b3, g2);
    rw2b_kernel<<<1024, 256, 0, stream>>>(g2, w4t, b4, bq, cb, fh, fl, cbh, cbl);
    vqm_kernel<<<2048, 256, 0, stream>>>(bq, fh, fl, cbh, cbl, cb, cnorm, latent, idxf);
}

// Round 14
// 1394.638 us; speedup vs baseline: 1.4174x; 1.4174x over previous
//
#include <hip/hip_runtime.h>
#include <math.h>

// Shapes:
// x:  [8, 2, 2048, 256]
// L1: conv k(8,1) s(4,1) p(2,0): -> [8,48,512,256]; gelu; 1x1 ->96; GLU -> [8,48,512,256]  (y1, ws)
// L2: conv -> [8,96,128,256]; gelu (g2, staged in d_out latent region); 1x1 ->192; GLU -> beforvq (d_out)
// VQ: argmin over 1024 codes of ||f - c||^2, latent = codebook[idx]
//
// d_out layout (fp32): latent [25165824] | indices-as-float [262144] | beforvq [25165824]

#define H1IN 2048
#define H1OUT 512
#define H2IN 512
#define H2OUT 128
#define TT 256
#define NPTS 32768           // 128*256 per batch
#define LAT_ELEMS 25165824   // 8*96*128*256
#define IDX_ELEMS 262144

typedef unsigned int uint;
typedef unsigned short ushort_t;
typedef __attribute__((ext_vector_type(8))) short bf16x8;
typedef __attribute__((ext_vector_type(4))) float f32x4;

// fp32 -> bf16 round-to-nearest-even (finite inputs)
__device__ __forceinline__ ushort_t f2bf(float x) {
    uint u = __float_as_uint(x);
    return (ushort_t)((u + 0x7fffu + ((u >> 16) & 1u)) >> 16);
}
__device__ __forceinline__ float bf2f(ushort_t h) {
    return __uint_as_float((uint)h << 16);
}

// ---------------- prep: transpose weights, codebook norms ----------------
__global__ __launch_bounds__(256) void prep_kernel(
    const float* __restrict__ w1, const float* __restrict__ w2,
    const float* __restrict__ w3, const float* __restrict__ w4,
    const float* __restrict__ cb,
    float* __restrict__ w1t, float* __restrict__ w2t,
    float* __restrict__ w3t, float* __restrict__ w4t,
    float* __restrict__ cnorm)
{
    int i = blockIdx.x * 256 + threadIdx.x;
    if (i < 768) {                       // w1t[(ci*8+kh)*48+oc] = w1[(oc*2+ci)*8+kh]
        int oc = i % 48; int r = i / 48;
        w1t[i] = w1[(oc * 2 + (r >> 3)) * 8 + (r & 7)];
    } else if (i < 5376) {               // w2t[c*96+oc] = w2[oc*48+c]
        int j = i - 768;
        int oc = j % 96, c = j / 96;
        w2t[j] = w2[oc * 48 + c];
    } else if (i < 42240) {              // w3t[(ci*8+kh)*96+oc] = w3[(oc*48+ci)*8+kh]
        int j = i - 5376;
        int oc = j % 96; int r = j / 96;
        w3t[j] = w3[(oc * 48 + (r >> 3)) * 8 + (r & 7)];
    } else if (i < 60672) {              // w4t[c*192+oc] = w4[oc*96+c]
        int j = i - 42240;
        int oc = j % 192, c = j / 192;
        w4t[j] = w4[oc * 96 + c];
    } else if (i < 61696) {              // cnorm[k] = sum_d cb[k][d]^2 (fp64 accumulate)
        int k = i - 60672;
        const float* cp = cb + (size_t)k * 96;
        double s = 0.0;
        for (int d = 0; d < 96; d++) s += (double)cp[d] * (double)cp[d];
        cnorm[k] = (float)s;
    }
}

__device__ __forceinline__ float gelu_tanh(float v) {
    float u = 0.7978845608028654f * (v + 0.044715f * v * v * v);
    return 0.5f * v * (1.f + tanhf(u));
}

// ---------------- layer 1 fused: conv + gelu + 1x1 + GLU ----------------
// R14 rewrite: spill-PROOF. R13 build showed henc1 at VGPR=68/870us though
// source was unchanged since R0 -- co-compiled-kernel regalloc perturbation
// re-triggered the z[96] spill (launch_bounds alone is not robust). Old
// structure: g[48] -> LDS (gs was written and read at the SAME address by
// the SAME thread -- a register-relief valve, 48KB, capping occupancy at 3
// blocks/CU) -> z[96] (the fragile 96-wide live range).
// New structure: hold the 16 input taps xv[16] in regs; 3 passes of 16 GLU
// pairs (za[16]+zb[16] = 32 accumulators); recompute the 16-FMA conv
// reduction g_c on the fly per channel (same FMA order -> bitwise-identical
// z). Peak live ~56 regs -> compiles clean at ANY allocator budget; no LDS
// -> occupancy VGPR-bound (~8 blocks/CU at 64 VGPR, was 3). Cost: conv
// redone 3x (+1.5k FMA/thread, +30% VALU) -- cheap vs spill immunity.
// All w1t/w2t/b1/b2 indices derive from loop induction vars -> s_load.
__global__ __launch_bounds__(256, 4) void henc1_kernel(
    const float* __restrict__ x, const float* __restrict__ w1t,
    const float* __restrict__ b1, const float* __restrict__ w2t,
    const float* __restrict__ b2, float* __restrict__ y1)
{
    int bh = blockIdx.x;           // b*512 + ho
    int ho = bh & 511, b = bh >> 9;
    int t = threadIdx.x;

    const float* xb = x + (size_t)b * 2 * H1IN * TT;
    int hbase = ho * 4 - 2;
    float xv[16];
#pragma unroll
    for (int ci = 0; ci < 2; ci++) {
#pragma unroll
        for (int kh = 0; kh < 8; kh++) {
            int hi = hbase + kh;
            xv[ci * 8 + kh] = (hi >= 0 && hi < H1IN)
                ? xb[((size_t)ci * H1IN + hi) * TT + t] : 0.f;
        }
    }

    float* yb = y1 + (size_t)b * 48 * H1OUT * TT + (size_t)ho * TT + t;

#pragma unroll 1
    for (int pass = 0; pass < 3; pass++) {
        int co0 = pass * 16;
        float za[16], zb[16];
#pragma unroll
        for (int j = 0; j < 16; j++) {
            za[j] = b2[co0 + j];
            zb[j] = b2[48 + co0 + j];
        }
#pragma unroll 1
        for (int c = 0; c < 48; c++) {
            float gc = b1[c];
#pragma unroll
            for (int i = 0; i < 16; i++) gc = fmaf(xv[i], w1t[i * 48 + c], gc);
            gc = gelu_tanh(gc);
            const float* wp = w2t + c * 96;
#pragma unroll
            for (int j = 0; j < 16; j++) {
                za[j] = fmaf(gc, wp[co0 + j], za[j]);
                zb[j] = fmaf(gc, wp[48 + co0 + j], zb[j]);
            }
        }
#pragma unroll
        for (int j = 0; j < 16; j++) {
            float o = za[j] / (1.f + expf(-zb[j]));   // a * sigmoid(b)
            yb[(size_t)(co0 + j) * H1OUT * TT] = o;
        }
    }
}

// ---------------- layer 2 conv + gelu ----------------
__global__ __launch_bounds__(256, 2) void conv2a_kernel(
    const float* __restrict__ y1, const float* __restrict__ w3t,
    const float* __restrict__ b3, float* __restrict__ g2)
{
    int bh = blockIdx.x;           // b*128 + ho
    int ho = bh & 127, b = bh >> 7;
    int t = threadIdx.x;

    float g[96];
#pragma unroll
    for (int oc = 0; oc < 96; oc++) g[oc] = b3[oc];

    const float* xb = y1 + (size_t)b * 48 * H2IN * TT;
    int hbase = ho * 4 - 2;
    for (int kh = 0; kh < 8; kh++) {
        int hi = hbase + kh;
        if (hi < 0 || hi >= H2IN) continue;       // wave-uniform branch
        const float* xr = xb + (size_t)hi * TT + t;
        for (int ci = 0; ci < 48; ci++) {
            float v = xr[(size_t)ci * H2IN * TT];
            const float* wp = w3t + (ci * 8 + kh) * 96;
#pragma unroll
            for (int oc = 0; oc < 96; oc++) g[oc] = fmaf(v, wp[oc], g[oc]);
        }
    }

    float* gp = g2 + (size_t)b * 96 * NPTS + (size_t)ho * TT + t;
#pragma unroll
    for (int oc = 0; oc < 96; oc++) gp[(size_t)oc * NPTS] = gelu_tanh(g[oc]);
}

// ---------------- layer 2 rewrite (1x1 -> 192) + GLU + bf16 hi/lo emit ----
__global__ __launch_bounds__(256, 2) void rw2b_kernel(
    const float* __restrict__ g2, const float* __restrict__ w4t,
    const float* __restrict__ b4, float* __restrict__ outv,
    const float* __restrict__ cb,
    ushort_t* __restrict__ fh, ushort_t* __restrict__ fl,
    ushort_t* __restrict__ cbh, ushort_t* __restrict__ cbl)
{
    int i = blockIdx.x * 256 + threadIdx.x;   // 0 .. 262143
    if (i < 98304) {                          // codebook bf16 hi/lo split
        float xv = cb[i];
        ushort_t h = f2bf(xv);
        cbh[i] = h;
        cbl[i] = f2bf(xv - bf2f(h));
    }

    int b = i >> 15, p = i & 32767;
    const float* gp = g2 + (size_t)b * 96 * NPTS + p;
    float* op = outv + (size_t)b * 96 * NPTS + p;

    for (int half = 0; half < 2; half++) {
        float za[48], zb[48];
#pragma unroll
        for (int j = 0; j < 48; j++) {
            za[j] = b4[half * 48 + j];
            zb[j] = b4[96 + half * 48 + j];
        }
        for (int c = 0; c < 96; c++) {
            float v = gp[(size_t)c * NPTS];
            const float* wp = w4t + c * 192;
#pragma unroll
            for (int j = 0; j < 48; j++) {
                za[j] = fmaf(v, wp[half * 48 + j], za[j]);
                zb[j] = fmaf(v, wp[96 + half * 48 + j], zb[j]);
            }
        }
        uint* fhp = (uint*)(fh + (size_t)i * 96 + half * 48);
        uint* flp = (uint*)(fl + (size_t)i * 96 + half * 48);
#pragma unroll
        for (int q = 0; q < 24; q++) {
            float o0 = za[2 * q]     / (1.f + expf(-zb[2 * q]));
            float o1 = za[2 * q + 1] / (1.f + expf(-zb[2 * q + 1]));
            op[(size_t)(half * 48 + 2 * q)     * NPTS] = o0;
            op[(size_t)(half * 48 + 2 * q + 1) * NPTS] = o1;
            ushort_t h0 = f2bf(o0); ushort_t l0 = f2bf(o0 - bf2f(h0));
            ushort_t h1 = f2bf(o1); ushort_t l1 = f2bf(o1 - bf2f(h1));
            fhp[q] = (uint)h0 | ((uint)h1 << 16);
            flp[q] = (uint)l0 | ((uint)l1 << 16);
        }
    }
}

// ---------------- VQ via MFMA: bf16 hi/lo screen + fp64 top-4 rescore ----
// R14: byte-revert to the R12 vqm (PASSED, 477us measured). R13's 32-point
// M-blocking showed no measurable gain (residual arithmetic: vqm ~500-590)
// and its build perturbed henc1's regalloc (rule: co-compiled kernels share
// regalloc context). Keeping the verified 16-point + 1-deep-pipeline form.
__global__ __launch_bounds__(256, 3) void vqm_kernel(
    const float* __restrict__ bq,
    const ushort_t* __restrict__ fh, const ushort_t* __restrict__ fl,
    const ushort_t* __restrict__ cbh, const ushort_t* __restrict__ cbl,
    const float* __restrict__ cb, const float* __restrict__ cnorm,
    float* __restrict__ latent, float* __restrict__ idxf)
{
    __shared__ float mbuf[4][16][8];     // [wave][point][4 s | 4 k]
    int tid = threadIdx.x;
    int lane = tid & 63;
    int wid = __builtin_amdgcn_readfirstlane(tid >> 6);   // 0..3 (R9 lesson)
    int lrow = lane & 15, lgrp = lane >> 4;
    int gp0 = blockIdx.x * 64;           // 4096 blocks; 512/batch -> no straddle
    int b = gp0 >> 15, p0 = gp0 & 32767;
    int pbase = gp0 + wid * 16;          // wave's 16 global points

    // ---- A fragments: point = pbase+lrow, dims kk*32 + 8*lgrp .. +7 ----
    bf16x8 ah[3], al[3];
    {
        const ushort_t* ph = fh + (size_t)(pbase + lrow) * 96 + 8 * lgrp;
        const ushort_t* pl = fl + (size_t)(pbase + lrow) * 96 + 8 * lgrp;
#pragma unroll
        for (int kk = 0; kk < 3; kk++) {
            ah[kk] = *(const bf16x8*)(ph + kk * 32);
            al[kk] = *(const bf16x8*)(pl + kk * 32);
        }
    }

    float bs[4][4]; int bk[4][4];        // per r: sorted ascending top-4
#pragma unroll
    for (int r = 0; r < 4; r++)
#pragma unroll
        for (int j = 0; j < 4; j++) { bs[r][j] = 3.402823466e+38f; bk[r][j] = 0x7fffffff; }

    // ---- pipelined ct loop: prefetch ct+1 while MFMAing ct ----
    const ushort_t* qh = cbh + (size_t)lrow * 96 + 8 * lgrp;
    const ushort_t* ql = cbl + (size_t)lrow * 96 + 8 * lgrp;
    const float* cnp = cnorm + lrow;

    bf16x8 nbh0 = *(const bf16x8*)(qh);
    bf16x8 nbh1 = *(const bf16x8*)(qh + 32);
    bf16x8 nbh2 = *(const bf16x8*)(qh + 64);
    bf16x8 nbl0 = *(const bf16x8*)(ql);
    bf16x8 nbl1 = *(const bf16x8*)(ql + 32);
    bf16x8 nbl2 = *(const bf16x8*)(ql + 64);
    float ncn = *cnp;

#pragma unroll 1
    for (int ct = 0; ct < 64; ct++) {
        bf16x8 bh0 = nbh0, bh1 = nbh1, bh2 = nbh2;
        bf16x8 bl0 = nbl0, bl1 = nbl1, bl2 = nbl2;
        float cn = ncn;
        int code = ct * 16 + lrow;

        if (ct < 63) {                   // issue next tile's loads early
            qh += 16 * 96; ql += 16 * 96; cnp += 16;
            nbh0 = *(const bf16x8*)(qh);
            nbh1 = *(const bf16x8*)(qh + 32);
            nbh2 = *(const bf16x8*)(qh + 64);
            nbl0 = *(const bf16x8*)(ql);
            nbl1 = *(const bf16x8*)(ql + 32);
            nbl2 = *(const bf16x8*)(ql + 64);
            ncn = *cnp;
        }

        f32x4 acc = {0.f, 0.f, 0.f, 0.f};
        acc = __builtin_amdgcn_mfma_f32_16x16x32_bf16(ah[0], bh0, acc, 0, 0, 0);
        acc = __builtin_amdgcn_mfma_f32_16x16x32_bf16(ah[1], bh1, acc, 0, 0, 0);
        acc = __builtin_amdgcn_mfma_f32_16x16x32_bf16(ah[2], bh2, acc, 0, 0, 0);
        acc = __builtin_amdgcn_mfma_f32_16x16x32_bf16(ah[0], bl0, acc, 0, 0, 0);
        acc = __builtin_amdgcn_mfma_f32_16x16x32_bf16(ah[1], bl1, acc, 0, 0, 0);
        acc = __builtin_amdgcn_mfma_f32_16x16x32_bf16(ah[2], bl2, acc, 0, 0, 0);
        acc = __builtin_amdgcn_mfma_f32_16x16x32_bf16(al[0], bh0, acc, 0, 0, 0);
        acc = __builtin_amdgcn_mfma_f32_16x16x32_bf16(al[1], bh1, acc, 0, 0, 0);
        acc = __builtin_amdgcn_mfma_f32_16x16x32_bf16(al[2], bh2, acc, 0, 0, 0);

#pragma unroll
        for (int r = 0; r < 4; r++) {
            float s = fmaf(-2.f, acc[r], cn);
            if (s < bs[r][3]) {          // codes arrive in ascending k; strict <
                bs[r][3] = s; bk[r][3] = code;
                if (bs[r][3] < bs[r][2]) {
                    float ts = bs[r][2]; bs[r][2] = bs[r][3]; bs[r][3] = ts;
                    int   tk = bk[r][2]; bk[r][2] = bk[r][3]; bk[r][3] = tk;
                    if (bs[r][2] < bs[r][1]) {
                        ts = bs[r][1]; bs[r][1] = bs[r][2]; bs[r][2] = ts;
                        tk = bk[r][1]; bk[r][1] = bk[r][2]; bk[r][2] = tk;
                        if (bs[r][1] < bs[r][0]) {
                            ts = bs[r][0]; bs[r][0] = bs[r][1]; bs[r][1] = ts;
                            tk = bk[r][0]; bk[r][0] = bk[r][1]; bk[r][1] = tk;
                        }
                    }
                }
            }
        }
    }

    // ---- butterfly merge of sorted top-4 across the 16 lanes (per r) ----
    // (s,k) comparator: smaller s wins; tie -> smaller k (global first-min).
#define CSW(si, ki, sj, kj) { bool c_ = (sj < si) || (sj == si && kj < ki); \
        float ls_ = c_ ? sj : si; float hs_ = c_ ? si : sj;                 \
        int   lk_ = c_ ? kj : ki; int   hk_ = c_ ? ki : kj;                 \
        si = ls_; ki = lk_; sj = hs_; kj = hk_; }
#pragma unroll
    for (int m = 1; m <= 8; m <<= 1) {
#pragma unroll
        for (int r = 0; r < 4; r++) {
            float os0 = __shfl_xor(bs[r][0], m), os1 = __shfl_xor(bs[r][1], m);
            float os2 = __shfl_xor(bs[r][2], m), os3 = __shfl_xor(bs[r][3], m);
            int   ok0 = __shfl_xor(bk[r][0], m), ok1 = __shfl_xor(bk[r][1], m);
            int   ok2 = __shfl_xor(bk[r][2], m), ok3 = __shfl_xor(bk[r][3], m);
            // bitonic stage 1: L_i = min(a_i, o_{3-i}) -> lowest 4, bitonic
            bool t0 = (bs[r][0] < os3) || (bs[r][0] == os3 && bk[r][0] < ok3);
            bool t1 = (bs[r][1] < os2) || (bs[r][1] == os2 && bk[r][1] < ok2);
            bool t2 = (bs[r][2] < os1) || (bs[r][2] == os1 && bk[r][2] < ok1);
            bool t3 = (bs[r][3] < os0) || (bs[r][3] == os0 && bk[r][3] < ok0);
            float L0s = t0 ? bs[r][0] : os3;  int L0k = t0 ? bk[r][0] : ok3;
            float L1s = t1 ? bs[r][1] : os2;  int L1k = t1 ? bk[r][1] : ok2;
            float L2s = t2 ? bs[r][2] : os1;  int L2k = t2 ? bk[r][2] : ok1;
            float L3s = t3 ? bs[r][3] : os0;  int L3k = t3 ? bk[r][3] : ok0;
            // bitonic sort-4
            CSW(L0s, L0k, L2s, L2k); CSW(L1s, L1k, L3s, L3k);
            CSW(L0s, L0k, L1s, L1k); CSW(L2s, L2k, L3s, L3k);
            bs[r][0] = L0s; bk[r][0] = L0k; bs[r][1] = L1s; bk[r][1] = L1k;
            bs[r][2] = L2s; bk[r][2] = L2k; bs[r][3] = L3s; bk[r][3] = L3k;
        }
    }
#undef CSW

    if (lrow == 0) {
#pragma unroll
        for (int r = 0; r < 4; r++) {
            int pt = lgrp * 4 + r;
#pragma unroll
            for (int j = 0; j < 4; j++) {
                mbuf[wid][pt][j] = bs[r][j];
                mbuf[wid][pt][4 + j] = (float)bk[r][j];   // k<=1023 exact
            }
        }
    }
    __syncthreads();

    // ---- fp64 rescore of the 4 candidates: lane = (point lrow, cand lgrp) ----
    int p = lrow;
    int kj = (int)mbuf[wid][p][4 + lgrp];
    const float* fpt = bq + (size_t)b * 96 * NPTS + (p0 + wid * 16 + p);
    const float* cj = cb + (size_t)kj * 96;
    double sd = 0.0;
    for (int d = 0; d < 96; d++) {
        double fd = (double)fpt[(size_t)d * NPTS];
        double xv = (double)cj[d];
        sd = fma(xv, xv - 2.0 * fd, sd);
    }
#pragma unroll
    for (int m = 16; m <= 32; m <<= 1) {
        double so = __shfl_xor(sd, m);
        int    ko = __shfl_xor(kj, m);
        if (so < sd || (so == sd && ko < kj)) { sd = so; kj = ko; }
    }
    if (lgrp == 0) idxf[gp0 + wid * 16 + p] = (float)kj;

    // ---- gather: lane writes 24 channels of its point ----
    const float* cbest = cb + (size_t)kj * 96;
    float* lp = latent + (size_t)b * 96 * NPTS + (p0 + wid * 16 + p);
#pragma unroll
    for (int i = 0; i < 24; i++) {
        int c = lgrp * 24 + i;
        lp[(size_t)c * NPTS] = cbest[c];
    }
}

extern "C" void kernel_launch(void* const* d_in, const int* in_sizes, int n_in,
                              void* d_out, int out_size, void* d_ws, size_t ws_size,
                              hipStream_t stream) {
    const float* x  = (const float*)d_in[0];
    const float* w1 = (const float*)d_in[1];
    const float* b1 = (const float*)d_in[2];
    const float* w2 = (const float*)d_in[3];
    const float* b2 = (const float*)d_in[4];
    const float* w3 = (const float*)d_in[5];
    const float* b3 = (const float*)d_in[6];
    const float* w4 = (const float*)d_in[7];
    const float* b4 = (const float*)d_in[8];
    const float* cb = (const float*)d_in[9];

    float* ws    = (float*)d_ws;
    float* y1    = ws;                       // 50331648 floats (201 MB); dead after conv2a
    float* w1t   = ws + 50331648;            // 768
    float* w2t   = w1t + 768;                // 4608
    float* w3t   = w2t + 4608;               // 36864
    float* w4t   = w3t + 36864;              // 18432
    float* cnorm = w4t + 18432;              // 1024

    // bf16 planes live in the dead y1 region (written by rw2b, after conv2a):
    ushort_t* fh  = (ushort_t*)ws;                    // 25165824 bf16 = 12582912 floats
    ushort_t* fl  = (ushort_t*)(ws + 12582912);       // 25165824 bf16
    ushort_t* cbh = (ushort_t*)(ws + 25165824);       // 98304 bf16 = 49152 floats
    ushort_t* cbl = (ushort_t*)(ws + 25165824 + 49152);

    float* out    = (float*)d_out;
    float* latent = out;
    float* idxf   = out + LAT_ELEMS;
    float* bq     = out + LAT_ELEMS + IDX_ELEMS;
    float* g2     = latent;   // latent region dead until vqm; reuse as conv2 scratch

    prep_kernel<<<241, 256, 0, stream>>>(w1, w2, w3, w4, cb, w1t, w2t, w3t, w4t, cnorm);
    henc1_kernel<<<8 * 512, 256, 0, stream>>>(x, w1t, b1, w2t, b2, y1);
    conv2a_kernel<<<8 * 128, 256, 0, stream>>>(y1, w3t, b3, g2);
    rw2b_kernel<<<1024, 256, 0, stream>>>(g2, w4t, b4, bq, cb, fh, fl, cbh, cbl);
    vqm_kernel<<<4096, 256, 0, stream>>>(bq, fh, fl, cbh, cbl, cb, cnorm, latent, idxf);
}

// Round 15
// 1329.954 us; speedup vs baseline: 1.4863x; 1.0486x over previous
//
#include <hip/hip_runtime.h>
#include <math.h>

// Shapes:
// x:  [8, 2, 2048, 256]
// L1: conv k(8,1) s(4,1) p(2,0): -> [8,48,512,256]; gelu; 1x1 ->96; GLU -> [8,48,512,256]  (y1, ws)
// L2: conv -> [8,96,128,256]; gelu (g2, staged in d_out latent region); 1x1 ->192; GLU -> beforvq (d_out)
// VQ: argmin over 1024 codes of ||f - c||^2, latent = codebook[idx]
//
// d_out layout (fp32): latent [25165824] | indices-as-float [262144] | beforvq [25165824]

#define H1IN 2048
#define H1OUT 512
#define H2IN 512
#define H2OUT 128
#define TT 256
#define NPTS 32768           // 128*256 per batch
#define LAT_ELEMS 25165824   // 8*96*128*256
#define IDX_ELEMS 262144

typedef unsigned int uint;
typedef unsigned short ushort_t;
typedef __attribute__((ext_vector_type(8))) short bf16x8;
typedef __attribute__((ext_vector_type(4))) float f32x4;

// fp32 -> bf16 round-to-nearest-even (finite inputs)
__device__ __forceinline__ ushort_t f2bf(float x) {
    uint u = __float_as_uint(x);
    return (ushort_t)((u + 0x7fffu + ((u >> 16) & 1u)) >> 16);
}
__device__ __forceinline__ float bf2f(ushort_t h) {
    return __uint_as_float((uint)h << 16);
}

// ---------------- prep: transpose weights, codebook norms ----------------
__global__ __launch_bounds__(256) void prep_kernel(
    const float* __restrict__ w1, const float* __restrict__ w2,
    const float* __restrict__ w3, const float* __restrict__ w4,
    const float* __restrict__ cb,
    float* __restrict__ w1t, float* __restrict__ w2t,
    float* __restrict__ w3t, float* __restrict__ w4t,
    float* __restrict__ cnorm)
{
    int i = blockIdx.x * 256 + threadIdx.x;
    if (i < 768) {                       // w1t[(ci*8+kh)*48+oc] = w1[(oc*2+ci)*8+kh]
        int oc = i % 48; int r = i / 48;
        w1t[i] = w1[(oc * 2 + (r >> 3)) * 8 + (r & 7)];
    } else if (i < 5376) {               // w2t[c*96+oc] = w2[oc*48+c]
        int j = i - 768;
        int oc = j % 96, c = j / 96;
        w2t[j] = w2[oc * 48 + c];
    } else if (i < 42240) {              // w3t[(ci*8+kh)*96+oc] = w3[(oc*48+ci)*8+kh]
        int j = i - 5376;
        int oc = j % 96; int r = j / 96;
        w3t[j] = w3[(oc * 48 + (r >> 3)) * 8 + (r & 7)];
    } else if (i < 60672) {              // w4t[c*192+oc] = w4[oc*96+c]
        int j = i - 42240;
        int oc = j % 192, c = j / 192;
        w4t[j] = w4[oc * 96 + c];
    } else if (i < 61696) {              // cnorm[k] = sum_d cb[k][d]^2 (fp64 accumulate)
        int k = i - 60672;
        const float* cp = cb + (size_t)k * 96;
        double s = 0.0;
        for (int d = 0; d < 96; d++) s += (double)cp[d] * (double)cp[d];
        cnorm[k] = (float)s;
    }
}

__device__ __forceinline__ float gelu_tanh(float v) {
    float u = 0.7978845608028654f * (v + 0.044715f * v * v * v);
    return 0.5f * v * (1.f + tanhf(u));
}

// ---------------- layer 1 fused: conv + gelu + 1x1 + GLU ----------------
// R14 spill-proof form (kept verbatim; henc1 left the top-5 after this).
// 3 passes of 16 GLU pairs; conv recomputed per pass (same FMA order ->
// bitwise-identical z). Peak live ~56 regs; no LDS.
__global__ __launch_bounds__(256, 4) void henc1_kernel(
    const float* __restrict__ x, const float* __restrict__ w1t,
    const float* __restrict__ b1, const float* __restrict__ w2t,
    const float* __restrict__ b2, float* __restrict__ y1)
{
    int bh = blockIdx.x;           // b*512 + ho
    int ho = bh & 511, b = bh >> 9;
    int t = threadIdx.x;

    const float* xb = x + (size_t)b * 2 * H1IN * TT;
    int hbase = ho * 4 - 2;
    float xv[16];
#pragma unroll
    for (int ci = 0; ci < 2; ci++) {
#pragma unroll
        for (int kh = 0; kh < 8; kh++) {
            int hi = hbase + kh;
            xv[ci * 8 + kh] = (hi >= 0 && hi < H1IN)
                ? xb[((size_t)ci * H1IN + hi) * TT + t] : 0.f;
        }
    }

    float* yb = y1 + (size_t)b * 48 * H1OUT * TT + (size_t)ho * TT + t;

#pragma unroll 1
    for (int pass = 0; pass < 3; pass++) {
        int co0 = pass * 16;
        float za[16], zb[16];
#pragma unroll
        for (int j = 0; j < 16; j++) {
            za[j] = b2[co0 + j];
            zb[j] = b2[48 + co0 + j];
        }
#pragma unroll 1
        for (int c = 0; c < 48; c++) {
            float gc = b1[c];
#pragma unroll
            for (int i = 0; i < 16; i++) gc = fmaf(xv[i], w1t[i * 48 + c], gc);
            gc = gelu_tanh(gc);
            const float* wp = w2t + c * 96;
#pragma unroll
            for (int j = 0; j < 16; j++) {
                za[j] = fmaf(gc, wp[co0 + j], za[j]);
                zb[j] = fmaf(gc, wp[48 + co0 + j], zb[j]);
            }
        }
#pragma unroll
        for (int j = 0; j < 16; j++) {
            float o = za[j] / (1.f + expf(-zb[j]));   // a * sigmoid(b)
            yb[(size_t)(co0 + j) * H1OUT * TT] = o;
        }
    }
}

// ---------------- layer 2 conv + gelu ----------------
__global__ __launch_bounds__(256, 2) void conv2a_kernel(
    const float* __restrict__ y1, const float* __restrict__ w3t,
    const float* __restrict__ b3, float* __restrict__ g2)
{
    int bh = blockIdx.x;           // b*128 + ho
    int ho = bh & 127, b = bh >> 7;
    int t = threadIdx.x;

    float g[96];
#pragma unroll
    for (int oc = 0; oc < 96; oc++) g[oc] = b3[oc];

    const float* xb = y1 + (size_t)b * 48 * H2IN * TT;
    int hbase = ho * 4 - 2;
    for (int kh = 0; kh < 8; kh++) {
        int hi = hbase + kh;
        if (hi < 0 || hi >= H2IN) continue;       // wave-uniform branch
        const float* xr = xb + (size_t)hi * TT + t;
        for (int ci = 0; ci < 48; ci++) {
            float v = xr[(size_t)ci * H2IN * TT];
            const float* wp = w3t + (ci * 8 + kh) * 96;
#pragma unroll
            for (int oc = 0; oc < 96; oc++) g[oc] = fmaf(v, wp[oc], g[oc]);
        }
    }

    float* gp = g2 + (size_t)b * 96 * NPTS + (size_t)ho * TT + t;
#pragma unroll
    for (int oc = 0; oc < 96; oc++) gp[(size_t)oc * NPTS] = gelu_tanh(g[oc]);
}

// ---------------- layer 2 rewrite (1x1 -> 192) + GLU + bf16 hi/lo emit ----
__global__ __launch_bounds__(256, 2) void rw2b_kernel(
    const float* __restrict__ g2, const float* __restrict__ w4t,
    const float* __restrict__ b4, float* __restrict__ outv,
    const float* __restrict__ cb,
    ushort_t* __restrict__ fh, ushort_t* __restrict__ fl,
    ushort_t* __restrict__ cbh, ushort_t* __restrict__ cbl)
{
    int i = blockIdx.x * 256 + threadIdx.x;   // 0 .. 262143
    if (i < 98304) {                          // codebook bf16 hi/lo split
        float xv = cb[i];
        ushort_t h = f2bf(xv);
        cbh[i] = h;
        cbl[i] = f2bf(xv - bf2f(h));
    }

    int b = i >> 15, p = i & 32767;
    const float* gp = g2 + (size_t)b * 96 * NPTS + p;
    float* op = outv + (size_t)b * 96 * NPTS + p;

    for (int half = 0; half < 2; half++) {
        float za[48], zb[48];
#pragma unroll
        for (int j = 0; j < 48; j++) {
            za[j] = b4[half * 48 + j];
            zb[j] = b4[96 + half * 48 + j];
        }
        for (int c = 0; c < 96; c++) {
            float v = gp[(size_t)c * NPTS];
            const float* wp = w4t + c * 192;
#pragma unroll
            for (int j = 0; j < 48; j++) {
                za[j] = fmaf(v, wp[half * 48 + j], za[j]);
                zb[j] = fmaf(v, wp[96 + half * 48 + j], zb[j]);
            }
        }
        uint* fhp = (uint*)(fh + (size_t)i * 96 + half * 48);
        uint* flp = (uint*)(fl + (size_t)i * 96 + half * 48);
#pragma unroll
        for (int q = 0; q < 24; q++) {
            float o0 = za[2 * q]     / (1.f + expf(-zb[2 * q]));
            float o1 = za[2 * q + 1] / (1.f + expf(-zb[2 * q + 1]));
            op[(size_t)(half * 48 + 2 * q)     * NPTS] = o0;
            op[(size_t)(half * 48 + 2 * q + 1) * NPTS] = o1;
            ushort_t h0 = f2bf(o0); ushort_t l0 = f2bf(o0 - bf2f(h0));
            ushort_t h1 = f2bf(o1); ushort_t l1 = f2bf(o1 - bf2f(h1));
            fhp[q] = (uint)h0 | ((uint)h1 << 16);
            flp[q] = (uint)l0 | ((uint)l1 << 16);
        }
    }
}

// ---------------- VQ via MFMA: bf16 hi/lo screen + fp64 top-4 rescore ----
// R15 = R14 vqm (PASSED, ~485us) with the 9-deep serial MFMA chain split
// into 3 INDEPENDENT accumulator chains. R14 counters: MfmaUtil 14% vs a
// 75us matrix-pipe floor (485us wall) -- all 9 MFMAs accumulated into ONE
// acc, so each waited on the previous writeback; at ~3.4 waves/SIMD the
// bubbles don't fill cross-wave. Split: accA=SUM ah.bh, accB=SUM ah.bl,
// accC=SUM al.bh (interleaved A/B/C -> consecutive MFMAs independent);
// combine with two f32x4 adds before the screen. Same 9 products, summed
// in different order -- screen-only (top-4 + fp64 always-rescore absorbs
// rounding differences). +8 VGPR, +2 adds/ct.
// Guards: WRITE ~99MB (spill); vqm unchanged +-30 -> dep-chain theory
// wrong -> R16 LDS-staged codebook or leaner screen.
__global__ __launch_bounds__(256, 3) void vqm_kernel(
    const float* __restrict__ bq,
    const ushort_t* __restrict__ fh, const ushort_t* __restrict__ fl,
    const ushort_t* __restrict__ cbh, const ushort_t* __restrict__ cbl,
    const float* __restrict__ cb, const float* __restrict__ cnorm,
    float* __restrict__ latent, float* __restrict__ idxf)
{
    __shared__ float mbuf[4][16][8];     // [wave][point][4 s | 4 k]
    int tid = threadIdx.x;
    int lane = tid & 63;
    int wid = __builtin_amdgcn_readfirstlane(tid >> 6);   // 0..3 (R9 lesson)
    int lrow = lane & 15, lgrp = lane >> 4;
    int gp0 = blockIdx.x * 64;           // 4096 blocks; 512/batch -> no straddle
    int b = gp0 >> 15, p0 = gp0 & 32767;
    int pbase = gp0 + wid * 16;          // wave's 16 global points

    // ---- A fragments: point = pbase+lrow, dims kk*32 + 8*lgrp .. +7 ----
    bf16x8 ah[3], al[3];
    {
        const ushort_t* ph = fh + (size_t)(pbase + lrow) * 96 + 8 * lgrp;
        const ushort_t* pl = fl + (size_t)(pbase + lrow) * 96 + 8 * lgrp;
#pragma unroll
        for (int kk = 0; kk < 3; kk++) {
            ah[kk] = *(const bf16x8*)(ph + kk * 32);
            al[kk] = *(const bf16x8*)(pl + kk * 32);
        }
    }

    float bs[4][4]; int bk[4][4];        // per r: sorted ascending top-4
#pragma unroll
    for (int r = 0; r < 4; r++)
#pragma unroll
        for (int j = 0; j < 4; j++) { bs[r][j] = 3.402823466e+38f; bk[r][j] = 0x7fffffff; }

    // ---- pipelined ct loop: prefetch ct+1 while MFMAing ct ----
    const ushort_t* qh = cbh + (size_t)lrow * 96 + 8 * lgrp;
    const ushort_t* ql = cbl + (size_t)lrow * 96 + 8 * lgrp;
    const float* cnp = cnorm + lrow;

    bf16x8 nbh0 = *(const bf16x8*)(qh);
    bf16x8 nbh1 = *(const bf16x8*)(qh + 32);
    bf16x8 nbh2 = *(const bf16x8*)(qh + 64);
    bf16x8 nbl0 = *(const bf16x8*)(ql);
    bf16x8 nbl1 = *(const bf16x8*)(ql + 32);
    bf16x8 nbl2 = *(const bf16x8*)(ql + 64);
    float ncn = *cnp;

#pragma unroll 1
    for (int ct = 0; ct < 64; ct++) {
        bf16x8 bh0 = nbh0, bh1 = nbh1, bh2 = nbh2;
        bf16x8 bl0 = nbl0, bl1 = nbl1, bl2 = nbl2;
        float cn = ncn;
        int code = ct * 16 + lrow;

        if (ct < 63) {                   // issue next tile's loads early
            qh += 16 * 96; ql += 16 * 96; cnp += 16;
            nbh0 = *(const bf16x8*)(qh);
            nbh1 = *(const bf16x8*)(qh + 32);
            nbh2 = *(const bf16x8*)(qh + 64);
            nbl0 = *(const bf16x8*)(ql);
            nbl1 = *(const bf16x8*)(ql + 32);
            nbl2 = *(const bf16x8*)(ql + 64);
            ncn = *cnp;
        }

        // 3 independent MFMA chains (A: hi.hi, B: hi.lo, C: lo.hi),
        // interleaved so consecutive MFMAs never share an accumulator.
        f32x4 accA = {0.f, 0.f, 0.f, 0.f};
        f32x4 accB = {0.f, 0.f, 0.f, 0.f};
        f32x4 accC = {0.f, 0.f, 0.f, 0.f};
        accA = __builtin_amdgcn_mfma_f32_16x16x32_bf16(ah[0], bh0, accA, 0, 0, 0);
        accB = __builtin_amdgcn_mfma_f32_16x16x32_bf16(ah[0], bl0, accB, 0, 0, 0);
        accC = __builtin_amdgcn_mfma_f32_16x16x32_bf16(al[0], bh0, accC, 0, 0, 0);
        accA = __builtin_amdgcn_mfma_f32_16x16x32_bf16(ah[1], bh1, accA, 0, 0, 0);
        accB = __builtin_amdgcn_mfma_f32_16x16x32_bf16(ah[1], bl1, accB, 0, 0, 0);
        accC = __builtin_amdgcn_mfma_f32_16x16x32_bf16(al[1], bh1, accC, 0, 0, 0);
        accA = __builtin_amdgcn_mfma_f32_16x16x32_bf16(ah[2], bh2, accA, 0, 0, 0);
        accB = __builtin_amdgcn_mfma_f32_16x16x32_bf16(ah[2], bl2, accB, 0, 0, 0);
        accC = __builtin_amdgcn_mfma_f32_16x16x32_bf16(al[2], bh2, accC, 0, 0, 0);
        f32x4 acc = (accA + accB) + accC;

#pragma unroll
        for (int r = 0; r < 4; r++) {
            float s = fmaf(-2.f, acc[r], cn);
            if (s < bs[r][3]) {          // codes arrive in ascending k; strict <
                bs[r][3] = s; bk[r][3] = code;
                if (bs[r][3] < bs[r][2]) {
                    float ts = bs[r][2]; bs[r][2] = bs[r][3]; bs[r][3] = ts;
                    int   tk = bk[r][2]; bk[r][2] = bk[r][3]; bk[r][3] = tk;
                    if (bs[r][2] < bs[r][1]) {
                        ts = bs[r][1]; bs[r][1] = bs[r][2]; bs[r][2] = ts;
                        tk = bk[r][1]; bk[r][1] = bk[r][2]; bk[r][2] = tk;
                        if (bs[r][1] < bs[r][0]) {
                            ts = bs[r][0]; bs[r][0] = bs[r][1]; bs[r][1] = ts;
                            tk = bk[r][0]; bk[r][0] = bk[r][1]; bk[r][1] = tk;
                        }
                    }
                }
            }
        }
    }

    // ---- butterfly merge of sorted top-4 across the 16 lanes (per r) ----
    // (s,k) comparator: smaller s wins; tie -> smaller k (global first-min).
#define CSW(si, ki, sj, kj) { bool c_ = (sj < si) || (sj == si && kj < ki); \
        float ls_ = c_ ? sj : si; float hs_ = c_ ? si : sj;                 \
        int   lk_ = c_ ? kj : ki; int   hk_ = c_ ? ki : kj;                 \
        si = ls_; ki = lk_; sj = hs_; kj = hk_; }
#pragma unroll
    for (int m = 1; m <= 8; m <<= 1) {
#pragma unroll
        for (int r = 0; r < 4; r++) {
            float os0 = __shfl_xor(bs[r][0], m), os1 = __shfl_xor(bs[r][1], m);
            float os2 = __shfl_xor(bs[r][2], m), os3 = __shfl_xor(bs[r][3], m);
            int   ok0 = __shfl_xor(bk[r][0], m), ok1 = __shfl_xor(bk[r][1], m);
            int   ok2 = __shfl_xor(bk[r][2], m), ok3 = __shfl_xor(bk[r][3], m);
            // bitonic stage 1: L_i = min(a_i, o_{3-i}) -> lowest 4, bitonic
            bool t0 = (bs[r][0] < os3) || (bs[r][0] == os3 && bk[r][0] < ok3);
            bool t1 = (bs[r][1] < os2) || (bs[r][1] == os2 && bk[r][1] < ok2);
            bool t2 = (bs[r][2] < os1) || (bs[r][2] == os1 && bk[r][2] < ok1);
            bool t3 = (bs[r][3] < os0) || (bs[r][3] == os0 && bk[r][3] < ok0);
            float L0s = t0 ? bs[r][0] : os3;  int L0k = t0 ? bk[r][0] : ok3;
            float L1s = t1 ? bs[r][1] : os2;  int L1k = t1 ? bk[r][1] : ok2;
            float L2s = t2 ? bs[r][2] : os1;  int L2k = t2 ? bk[r][2] : ok1;
            float L3s = t3 ? bs[r][3] : os0;  int L3k = t3 ? bk[r][3] : ok0;
            // bitonic sort-4
            CSW(L0s, L0k, L2s, L2k); CSW(L1s, L1k, L3s, L3k);
            CSW(L0s, L0k, L1s, L1k); CSW(L2s, L2k, L3s, L3k);
            bs[r][0] = L0s; bk[r][0] = L0k; bs[r][1] = L1s; bk[r][1] = L1k;
            bs[r][2] = L2s; bk[r][2] = L2k; bs[r][3] = L3s; bk[r][3] = L3k;
        }
    }
#undef CSW

    if (lrow == 0) {
#pragma unroll
        for (int r = 0; r < 4; r++) {
            int pt = lgrp * 4 + r;
#pragma unroll
            for (int j = 0; j < 4; j++) {
                mbuf[wid][pt][j] = bs[r][j];
                mbuf[wid][pt][4 + j] = (float)bk[r][j];   // k<=1023 exact
            }
        }
    }
    __syncthreads();

    // ---- fp64 rescore of the 4 candidates: lane = (point lrow, cand lgrp) ----
    int p = lrow;
    int kj = (int)mbuf[wid][p][4 + lgrp];
    const float* fpt = bq + (size_t)b * 96 * NPTS + (p0 + wid * 16 + p);
    const float* cj = cb + (size_t)kj * 96;
    double sd = 0.0;
    for (int d = 0; d < 96; d++) {
        double fd = (double)fpt[(size_t)d * NPTS];
        double xv = (double)cj[d];
        sd = fma(xv, xv - 2.0 * fd, sd);
    }
#pragma unroll
    for (int m = 16; m <= 32; m <<= 1) {
        double so = __shfl_xor(sd, m);
        int    ko = __shfl_xor(kj, m);
        if (so < sd || (so == sd && ko < kj)) { sd = so; kj = ko; }
    }
    if (lgrp == 0) idxf[gp0 + wid * 16 + p] = (float)kj;

    // ---- gather: lane writes 24 channels of its point ----
    const float* cbest = cb + (size_t)kj * 96;
    float* lp = latent + (size_t)b * 96 * NPTS + (p0 + wid * 16 + p);
#pragma unroll
    for (int i = 0; i < 24; i++) {
        int c = lgrp * 24 + i;
        lp[(size_t)c * NPTS] = cbest[c];
    }
}

extern "C" void kernel_launch(void* const* d_in, const int* in_sizes, int n_in,
                              void* d_out, int out_size, void* d_ws, size_t ws_size,
                              hipStream_t stream) {
    const float* x  = (const float*)d_in[0];
    const float* w1 = (const float*)d_in[1];
    const float* b1 = (const float*)d_in[2];
    const float* w2 = (const float*)d_in[3];
    const float* b2 = (const float*)d_in[4];
    const float* w3 = (const float*)d_in[5];
    const float* b3 = (const float*)d_in[6];
    const float* w4 = (const float*)d_in[7];
    const float* b4 = (const float*)d_in[8];
    const float* cb = (const float*)d_in[9];

    float* ws    = (float*)d_ws;
    float* y1    = ws;                       // 50331648 floats (201 MB); dead after conv2a
    float* w1t   = ws + 50331648;            // 768
    float* w2t   = w1t + 768;                // 4608
    float* w3t   = w2t + 4608;               // 36864
    float* w4t   = w3t + 36864;              // 18432
    float* cnorm = w4t + 18432;              // 1024

    // bf16 planes live in the dead y1 region (written by rw2b, after conv2a):
    ushort_t* fh  = (ushort_t*)ws;                    // 25165824 bf16 = 12582912 floats
    ushort_t* fl  = (ushort_t*)(ws + 12582912);       // 25165824 bf16
    ushort_t* cbh = (ushort_t*)(ws + 25165824);       // 98304 bf16 = 49152 floats
    ushort_t* cbl = (ushort_t*)(ws + 25165824 + 49152);

    float* out    = (float*)d_out;
    float* latent = out;
    float* idxf   = out + LAT_ELEMS;
    float* bq     = out + LAT_ELEMS + IDX_ELEMS;
    float* g2     = latent;   // latent region dead until vqm; reuse as conv2 scratch

    prep_kernel<<<241, 256, 0, stream>>>(w1, w2, w3, w4, cb, w1t, w2t, w3t, w4t, cnorm);
    henc1_kernel<<<8 * 512, 256, 0, stream>>>(x, w1t, b1, w2t, b2, y1);
    conv2a_kernel<<<8 * 128, 256, 0, stream>>>(y1, w3t, b3, g2);
    rw2b_kernel<<<1024, 256, 0, stream>>>(g2, w4t, b4, bq, cb, fh, fl, cbh, cbl);
    vqm_kernel<<<4096, 256, 0, stream>>>(bq, fh, fl, cbh, cbl, cb, cnorm, latent, idxf);
}